// Round 3
// baseline (94.129 us; speedup 1.0000x reference)
//
#include <hip/hip_runtime.h>

// input x: (B=256, T=600, J=25, C=3) f32; x[b,tt, n*5+p, c] = in[(b*600+tt)*75 + n*15 + p*3 + c]
// output: (B, 5, 1800, 4, 4) f32. For global time tt the 3 concatenated windows'
// outputs sit at tout = tt, 600+tt, 1200+tt; interior results are identical
// across windows, boundary slots use the center-only (5-sample) covariance.
//
// R3: 4 lanes per (b,n,tt) slot — one per output row — so each store
// instruction is lane-contiguous (16B/lane consecutive = dense 1KB/wave),
// fixing the 1.55x HBM write amplification seen in R2.

#define T_ 600
#define TILE_ 60     // tt slots per block (60 slots * 4 rows = 240 active threads)
#define TILES_ 10    // 600 / 60

__global__ __launch_bounds__(256) void gauss_agg_kernel(const float* __restrict__ x,
                                                        float* __restrict__ out) {
    int blk  = blockIdx.x;            // (b*5+n)*TILES_ + tile
    int tile = blk % TILES_;
    int bn   = blk / TILES_;          // b*5 + n
    int tid  = threadIdx.x;
    if (tid >= TILE_ * 4) return;
    int tl  = tid >> 2;
    int row = tid & 3;
    int tt  = tile * TILE_ + tl;
    int b = bn / 5;
    int n = bn - b * 5;

    const float* p0 = x + ((size_t)b * T_ + tt) * 75 + n * 15;

    // ---- center time: plain sum, outer-product sum, weighted (smoothed) mean ----
    float s0=0.f,s1=0.f,s2=0.f, m0=0.f,m1=0.f,m2=0.f;
    float A00=0.f,A01=0.f,A02=0.f,A11=0.f,A12=0.f,A22=0.f;
    const float w5[5] = {4.f, 2.f, 3.f, 2.f, 4.f};
    #pragma unroll
    for (int p = 0; p < 5; ++p) {
        float a = p0[p*3+0], c = p0[p*3+1], d = p0[p*3+2];
        s0 += a; s1 += c; s2 += d;
        m0 += w5[p]*a; m1 += w5[p]*c; m2 += w5[p]*d;
        A00 += a*a; A01 += a*c; A02 += a*d;
        A11 += c*c; A12 += c*d; A22 += d*d;
    }
    float mu0 = m0*(1.f/15.f), mu1 = m1*(1.f/15.f), mu2 = m2*(1.f/15.f);

    // snapshot center-only sums (window-boundary form)
    float cs0=s0, cs1=s1, cs2=s2;
    float cA00=A00, cA01=A01, cA02=A02, cA11=A11, cA12=A12, cA22=A22;

    bool edge = (tt == 0) || (tt == T_ - 1);
    if (!edge) {
        #pragma unroll
        for (int dstep = 0; dstep < 2; ++dstep) {
            const float* pn = p0 + (dstep ? 75 : -75);
            #pragma unroll
            for (int p = 0; p < 5; ++p) {
                float a = pn[p*3+0], c = pn[p*3+1], d = pn[p*3+2];
                s0 += a; s1 += c; s2 += d;
                A00 += a*a; A01 += a*c; A02 += a*d;
                A11 += c*c; A12 += c*d; A22 += d*d;
            }
        }
    }

    // center-only (boundary) moments, inv = 1/5
    float mb0=cs0*0.2f, mb1=cs1*0.2f, mb2=cs2*0.2f;
    float eC00 = cA00*0.2f - 2.f*mu0*mb0 + 2.f*mu0*mu0;
    float eC01 = cA01*0.2f - mu0*mb1 - mb0*mu1 + 2.f*mu0*mu1;
    float eC02 = cA02*0.2f - mu0*mb2 - mb0*mu2 + 2.f*mu0*mu2;
    float eC11 = cA11*0.2f - 2.f*mu1*mb1 + 2.f*mu1*mu1;
    float eC12 = cA12*0.2f - mu1*mb2 - mb1*mu2 + 2.f*mu1*mu2;
    float eC22 = cA22*0.2f - 2.f*mu2*mb2 + 2.f*mu2*mu2;

    // interior (3-time) moments, inv = 1/15 (garbage at edge tt, masked there)
    const float invI = 1.f/15.f;
    float mi0=s0*invI, mi1=s1*invI, mi2=s2*invI;
    float eI00 = A00*invI - 2.f*mu0*mi0 + 2.f*mu0*mu0;
    float eI01 = A01*invI - mu0*mi1 - mi0*mu1 + 2.f*mu0*mu1;
    float eI02 = A02*invI - mu0*mi2 - mi0*mu2 + 2.f*mu0*mu2;
    float eI11 = A11*invI - 2.f*mu1*mi1 + 2.f*mu1*mu1;
    float eI12 = A12*invI - mu1*mi2 - mi1*mu2 + 2.f*mu1*mu2;
    float eI22 = A22*invI - 2.f*mu2*mi2 + 2.f*mu2*mu2;

    // this lane's row of the 4x4 block (interior + boundary variants)
    float4 vI, vC;
    if (row == 0)      { vI = make_float4(eI00, eI01, eI02, mu0); vC = make_float4(eC00, eC01, eC02, mu0); }
    else if (row == 1) { vI = make_float4(eI01, eI11, eI12, mu1); vC = make_float4(eC01, eC11, eC12, mu1); }
    else if (row == 2) { vI = make_float4(eI02, eI12, eI22, mu2); vC = make_float4(eC02, eC12, eC22, mu2); }
    else               { vI = make_float4(mu0,  mu1,  mu2,  1.f); vC = vI; }

    // window-boundary masks (global tt)
    bool bd0 = edge;
    bool bd1 = edge || (tt == 299) || (tt == 300);
    bool bd2 = edge || (tt == 199) || (tt == 200) || (tt == 399) || (tt == 400);

    float4* of = reinterpret_cast<float4*>(out) + ((size_t)bn * 1800 + tt) * 4 + row;
    of[0]        = bd0 ? vC : vI;   // window group 0: tout = tt
    of[600 * 4]  = bd1 ? vC : vI;   // window group 1: tout = 600 + tt
    of[1200 * 4] = bd2 ? vC : vI;   // window group 2: tout = 1200 + tt
}

extern "C" void kernel_launch(void* const* d_in, const int* in_sizes, int n_in,
                              void* d_out, int out_size, void* d_ws, size_t ws_size,
                              hipStream_t stream) {
    const float* x = (const float*)d_in[0];
    float* out = (float*)d_out;
    int blocks = 256 * 5 * TILES_;   // 12800 blocks, 240/256 active threads
    gauss_agg_kernel<<<blocks, 256, 0, stream>>>(x, out);
}

// Round 4
// 84.450 us; speedup vs baseline: 1.1146x; 1.1146x over previous
//
#include <hip/hip_runtime.h>

// input x: (B=256,T=600,J=25,C=3) f32; x[b,tt,n*5+p,c] = in[(b*600+tt)*75 + n*15 + p*3 + c]
// output: (B,5,1800,4,4) f32, windows concatenated along tout.
//
// R4: block = one (b,n) output row; thread=slot walking tout 0..1799 in address
// order (R1's proven-clean write pattern, WRITE=1.01x). Fetch fixed by XCD-aware
// swizzle: the 5 blocks sharing batch b land on the same XCD (b%8 == blk%8) so
// b's 180KB input is L2-resident for all of them.

#define T_ 600

__global__ __launch_bounds__(256) void gauss_agg_kernel(const float* __restrict__ x,
                                                        float* __restrict__ out) {
    // swizzle: blk -> (b,n) with b%8 == blk%8 (same-XCD grouping per batch)
    int i = blockIdx.x;
    int oct = i & 7;          // xcd slot
    int j = i >> 3;           // 0..159
    int n = j % 5;
    int b = oct + 8 * (j / 5);

    const float* xb = x + (size_t)b * T_ * 75 + n * 15;
    float* orow = out + ((size_t)(b * 5 + n) * 1800) * 16;

    for (int r = 0; r < 8; ++r) {
        int s = r * 256 + (int)threadIdx.x;   // tout in [0,1800)
        if (s >= 1800) break;

        // window decode
        int rel, tt, Lw;
        if (s < 600)       { rel = s;        tt = rel;       Lw = 600; }
        else if (s < 900)  { rel = s - 600;  tt = rel;       Lw = 300; }
        else if (s < 1200) { rel = s - 900;  tt = 300 + rel; Lw = 300; }
        else if (s < 1400) { rel = s - 1200; tt = rel;       Lw = 200; }
        else if (s < 1600) { rel = s - 1400; tt = 200 + rel; Lw = 200; }
        else               { rel = s - 1600; tt = 400 + rel; Lw = 200; }
        bool boundary = (rel == 0) || (rel == Lw - 1);

        const float* p0 = xb + (size_t)tt * 75;

        float s0=0.f,s1=0.f,s2=0.f, m0=0.f,m1=0.f,m2=0.f;
        float A00=0.f,A01=0.f,A02=0.f,A11=0.f,A12=0.f,A22=0.f;
        const float w5[5] = {4.f, 2.f, 3.f, 2.f, 4.f};
        #pragma unroll
        for (int p = 0; p < 5; ++p) {
            float a = p0[p*3+0], c = p0[p*3+1], d = p0[p*3+2];
            s0 += a; s1 += c; s2 += d;
            m0 += w5[p]*a; m1 += w5[p]*c; m2 += w5[p]*d;
            A00 += a*a; A01 += a*c; A02 += a*d;
            A11 += c*c; A12 += c*d; A22 += d*d;
        }
        float mu0 = m0*(1.f/15.f), mu1 = m1*(1.f/15.f), mu2 = m2*(1.f/15.f);

        float inv = 0.2f;
        if (!boundary) {
            #pragma unroll
            for (int dstep = 0; dstep < 2; ++dstep) {
                const float* pn = p0 + (dstep ? 75 : -75);
                #pragma unroll
                for (int p = 0; p < 5; ++p) {
                    float a = pn[p*3+0], c = pn[p*3+1], d = pn[p*3+2];
                    s0 += a; s1 += c; s2 += d;
                    A00 += a*a; A01 += a*c; A02 += a*d;
                    A11 += c*c; A12 += c*d; A22 += d*d;
                }
            }
            inv = 1.f/15.f;
        }

        float mb0=s0*inv, mb1=s1*inv, mb2=s2*inv;
        float e00 = A00*inv - 2.f*mu0*mb0 + 2.f*mu0*mu0;
        float e01 = A01*inv - mu0*mb1 - mb0*mu1 + 2.f*mu0*mu1;
        float e02 = A02*inv - mu0*mb2 - mb0*mu2 + 2.f*mu0*mu2;
        float e11 = A11*inv - 2.f*mu1*mb1 + 2.f*mu1*mu1;
        float e12 = A12*inv - mu1*mb2 - mb1*mu2 + 2.f*mu1*mu2;
        float e22 = A22*inv - 2.f*mu2*mb2 + 2.f*mu2*mu2;

        float4* op = reinterpret_cast<float4*>(orow) + (size_t)s * 4;
        op[0] = make_float4(e00, e01, e02, mu0);
        op[1] = make_float4(e01, e11, e12, mu1);
        op[2] = make_float4(e02, e12, e22, mu2);
        op[3] = make_float4(mu0, mu1, mu2, 1.f);
    }
}

extern "C" void kernel_launch(void* const* d_in, const int* in_sizes, int n_in,
                              void* d_out, int out_size, void* d_ws, size_t ws_size,
                              hipStream_t stream) {
    const float* x = (const float*)d_in[0];
    float* out = (float*)d_out;
    gauss_agg_kernel<<<256 * 5, 256, 0, stream>>>(x, out);
}

// Round 5
// 65.753 us; speedup vs baseline: 1.4316x; 1.2843x over previous
//
#include <hip/hip_runtime.h>

// input x: (B=256,T=600,J=25,C=3) f32; x[b,tt,n*5+p,c] = in[(b*600+tt)*75 + n*15 + p*3 + c]
// output: (B,5,1800,4,4) f32, windows concatenated along tout.
//
// R5: block = one (b,n) output row (R4's proven-clean write pattern).
// Phase 1: per-tt moment stats (s[3], A[6], m[3]) computed once into LDS.
// Phase 2: each slot combines 1 or 3 stat rows via ds_read_b128 and stores.
// Stats row stride = 12 floats (48B): (12*tt) mod 32 sweeps 8 bank offsets
// -> uniform bank usage for b128 reads across consecutive-tt lanes.

#define T_ 600

__global__ __launch_bounds__(256) void gauss_agg_kernel(const float* __restrict__ x,
                                                        float* __restrict__ out) {
    __shared__ float4 st[T_ * 3];   // [tt][3] float4 = 12 floats/row, 28.8 KB

    // XCD swizzle: blocks sharing batch b land on the same XCD (b%8 == blk%8)
    int i = blockIdx.x;
    int oct = i & 7;
    int j = i >> 3;
    int n = j % 5;
    int b = oct + 8 * (j / 5);

    const float* xb = x + (size_t)b * T_ * 75 + n * 15;

    // ---- phase 1: per-tt stats ----
    const float w5[5] = {4.f, 2.f, 3.f, 2.f, 4.f};
    for (int tt = (int)threadIdx.x; tt < T_; tt += 256) {
        const float* p0 = xb + (size_t)tt * 75;
        float s0=0.f,s1=0.f,s2=0.f, m0=0.f,m1=0.f,m2=0.f;
        float A00=0.f,A01=0.f,A02=0.f,A11=0.f,A12=0.f,A22=0.f;
        #pragma unroll
        for (int p = 0; p < 5; ++p) {
            float a = p0[p*3+0], c = p0[p*3+1], d = p0[p*3+2];
            s0 += a; s1 += c; s2 += d;
            m0 += w5[p]*a; m1 += w5[p]*c; m2 += w5[p]*d;
            A00 += a*a; A01 += a*c; A02 += a*d;
            A11 += c*c; A12 += c*d; A22 += d*d;
        }
        st[tt*3 + 0] = make_float4(s0, s1, s2, A00);
        st[tt*3 + 1] = make_float4(A01, A02, A11, A12);
        st[tt*3 + 2] = make_float4(A22, m0, m1, m2);
    }
    __syncthreads();

    // ---- phase 2: combine + store (single contiguous stream per wave) ----
    float* orow = out + (size_t)(b * 5 + n) * 1800 * 16;
    for (int r = 0; r < 8; ++r) {
        int s = r * 256 + (int)threadIdx.x;   // tout in [0,1800)
        if (s >= 1800) break;

        int rel, tt, Lw;
        if (s < 600)       { rel = s;        tt = rel;       Lw = 600; }
        else if (s < 900)  { rel = s - 600;  tt = rel;       Lw = 300; }
        else if (s < 1200) { rel = s - 900;  tt = 300 + rel; Lw = 300; }
        else if (s < 1400) { rel = s - 1200; tt = rel;       Lw = 200; }
        else if (s < 1600) { rel = s - 1400; tt = 200 + rel; Lw = 200; }
        else               { rel = s - 1600; tt = 400 + rel; Lw = 200; }
        bool boundary = (rel == 0) || (rel == Lw - 1);

        float4 c0 = st[tt*3 + 0], c1 = st[tt*3 + 1], c2 = st[tt*3 + 2];
        float s0 = c0.x, s1 = c0.y, s2 = c0.z;
        float A00 = c0.w, A01 = c1.x, A02 = c1.y, A11 = c1.z, A12 = c1.w, A22 = c2.x;
        float mu0 = c2.y * (1.f/15.f), mu1 = c2.z * (1.f/15.f), mu2 = c2.w * (1.f/15.f);

        float inv = 0.2f;
        if (!boundary) {   // interior: tt in [1, T_-2] guaranteed
            float4 l0 = st[(tt-1)*3 + 0], l1 = st[(tt-1)*3 + 1], l2 = st[(tt-1)*3 + 2];
            float4 h0 = st[(tt+1)*3 + 0], h1 = st[(tt+1)*3 + 1], h2 = st[(tt+1)*3 + 2];
            s0 += l0.x + h0.x; s1 += l0.y + h0.y; s2 += l0.z + h0.z;
            A00 += l0.w + h0.w; A01 += l1.x + h1.x; A02 += l1.y + h1.y;
            A11 += l1.z + h1.z; A12 += l1.w + h1.w; A22 += l2.x + h2.x;
            inv = 1.f/15.f;
        }

        float mb0 = s0*inv, mb1 = s1*inv, mb2 = s2*inv;
        float e00 = A00*inv - 2.f*mu0*mb0 + 2.f*mu0*mu0;
        float e01 = A01*inv - mu0*mb1 - mb0*mu1 + 2.f*mu0*mu1;
        float e02 = A02*inv - mu0*mb2 - mb0*mu2 + 2.f*mu0*mu2;
        float e11 = A11*inv - 2.f*mu1*mb1 + 2.f*mu1*mu1;
        float e12 = A12*inv - mu1*mb2 - mb1*mu2 + 2.f*mu1*mu2;
        float e22 = A22*inv - 2.f*mu2*mb2 + 2.f*mu2*mu2;

        float4* op = reinterpret_cast<float4*>(orow) + (size_t)s * 4;
        op[0] = make_float4(e00, e01, e02, mu0);
        op[1] = make_float4(e01, e11, e12, mu1);
        op[2] = make_float4(e02, e12, e22, mu2);
        op[3] = make_float4(mu0, mu1, mu2, 1.f);
    }
}

extern "C" void kernel_launch(void* const* d_in, const int* in_sizes, int n_in,
                              void* d_out, int out_size, void* d_ws, size_t ws_size,
                              hipStream_t stream) {
    const float* x = (const float*)d_in[0];
    float* out = (float*)d_out;
    gauss_agg_kernel<<<256 * 5, 256, 0, stream>>>(x, out);
}